// Round 7
// baseline (866.981 us; speedup 1.0000x reference)
//
#include <hip/hip_runtime.h>
#include <math.h>

typedef __attribute__((ext_vector_type(8))) int   i32x8;
typedef __attribute__((ext_vector_type(4))) float f32x4;
typedef unsigned short ushortT;
typedef unsigned int uint32;
typedef unsigned char uchar;

#define KNN_K   5
#define DIM     128
#define FLT_BIG 3.402823466e38f
#define KEY_C   512.0f          // shift so acc = -(key+C)/2 is always negative

// ---------------- MFMA-path constants (fixed problem shape) ----------------
#define MF_B     2048
#define MF_N     100000
#define MF_QPB   256              // queries per block (4 waves x 64)
#define MF_QPW   64
#define MF_NCH   256              // train chunks (8 query-blocks each -> 2048 blocks)
#define MF_CHS   400              // rows per chunk; 256*400 = 102400 (padded)
#define MF_NPAD  (MF_NCH * MF_CHS)
#define MF_TILES 25
#define MF_CSLOT 4                // candidates kept per (query, chunk)
#define MF_NCAND (MF_NCH * MF_CSLOT)   // 1024 per query = 16/lane exactly
#define MF_RESCORE 16             // phase-B exact-rescore depth (fp8 key noise)
#define SCALE1   0x7F7F7F7Fu      // E8M0 exponent 127 -> x1.0 in every byte

__device__ __forceinline__ uint32 umn(uint32 a, uint32 b) { return a < b ? a : b; }
__device__ __forceinline__ uint32 umx(uint32 a, uint32 b) { return a > b ? a : b; }

// Static-index top-5 insertion for exact fp32 phase-B merge.
#define TOP5_INSERT(v, id)                                                  \
    if ((v) < bd4) {                                                        \
        bool l0 = (v) < bd0, l1 = (v) < bd1, l2 = (v) < bd2, l3 = (v) < bd3;\
        if (l3) { bd4 = bd3; bi4 = bi3; } else { bd4 = (v); bi4 = (id); }   \
        if (l2) { bd3 = bd2; bi3 = bi2; } else if (l3) { bd3 = (v); bi3 = (id); } \
        if (l1) { bd2 = bd1; bi2 = bi1; } else if (l2) { bd2 = (v); bi2 = (id); } \
        if (l0) { bd1 = bd0; bi1 = bi0; } else if (l1) { bd1 = (v); bi1 = (id); } \
        if (l0) { bd0 = (v); bi0 = (id); }                                  \
    }

// ------------------------------------------------------------------- fp8 cvt
#if defined(__has_builtin) && __has_builtin(__builtin_amdgcn_cvt_pk_fp8_f32)
#define HAVE_CVT_FP8 1
#else
#define HAVE_CVT_FP8 0
__device__ __forceinline__ uint32 f2fp8_u(float f) {
    uint32 u = __float_as_uint(f);
    uint32 s = (u >> 31) << 7;
    uint32 au = u & 0x7FFFFFFFu;
    float a = __uint_as_float(au);
    if (a >= 448.f) return s | 0x7Eu;
    int ex = (int)((au >> 23) & 0xFF) - 127;
    if (ex < -6) {
        int m = (int)(a * 512.f + 0.5f);
        return s | (uint32)(m > 7 ? 7 : m);
    }
    uint32 r = au + 0x7FFFFu + ((au >> 20) & 1u);
    ex = (int)((r >> 23) & 0xFF) - 127;
    if (ex > 8) return s | 0x7Eu;
    return s | ((uint32)(ex + 7) << 3) | ((r >> 20) & 7u);
}
#endif

// ------------------------------------------------------------------- prep
// One launch: blocks [0, MF_NPAD/64) convert train (+pad key poison),
// blocks [MF_NPAD/64, +B/64) convert x. 16 rows/wave, lane = 32 floats.
__global__ __launch_bounds__(256) void prep_kernel(
        const float* __restrict__ train, const float* __restrict__ x,
        uchar* __restrict__ tf8, uchar* __restrict__ xf8,
        float* __restrict__ t2c) {
    const int wv = threadIdx.x >> 6, lane = threadIdx.x & 63;
    const int tblocks = MF_NPAD / 64;
    const bool isx = (blockIdx.x >= tblocks);
    const int blk = isx ? (blockIdx.x - tblocks) : blockIdx.x;
    const int row = (blk * 4 + wv) * 16 + (lane >> 2);

    const float* src; uchar* dst;
    if (isx) {
        if (row >= MF_B) return;
        src = x; dst = xf8;
    } else {
        if (row >= MF_N) {                        // pad row: poison key only
            if (row < MF_NPAD && (lane & 3) == 0) t2c[row] = -1e30f;
            return;
        }
        src = train; dst = tf8;
    }
    const int seg = (lane & 3) * 32;              // 32 floats / 32 bytes
    const float4* p = (const float4*)(src + (size_t)row * DIM + seg);

    float4 v[8];
#pragma unroll
    for (int j = 0; j < 8; ++j) v[j] = p[j];

    uint32 d[8];
#pragma unroll
    for (int j = 0; j < 8; ++j) {
#if HAVE_CVT_FP8
        int r = __builtin_amdgcn_cvt_pk_fp8_f32(v[j].x, v[j].y, 0, false);
        r = __builtin_amdgcn_cvt_pk_fp8_f32(v[j].z, v[j].w, r, true);
        d[j] = (uint32)r;
#else
        d[j] = f2fp8_u(v[j].x) | (f2fp8_u(v[j].y) << 8)
             | (f2fp8_u(v[j].z) << 16) | (f2fp8_u(v[j].w) << 24);
#endif
    }
    uint4* o = (uint4*)(dst + (size_t)row * DIM + seg);
    o[0] = make_uint4(d[0], d[1], d[2], d[3]);
    o[1] = make_uint4(d[4], d[5], d[6], d[7]);

    if (!isx) {
        float s = 0.f;
#pragma unroll
        for (int j = 0; j < 8; ++j)
            s += v[j].x * v[j].x + v[j].y * v[j].y + v[j].z * v[j].z + v[j].w * v[j].w;
        s += __shfl_xor(s, 1);
        s += __shfl_xor(s, 2);
        if ((lane & 3) == 0) t2c[row] = -(s + KEY_C) * 0.5f;
    }
}

// ---------------------------------------------------------------- phase A
// MX-fp8 K=128, XCD-affinity grid mapping (FETCH 104->15 MB, round 5).
// acc init = t2c = -(t2+C)/2 -> final acc = -(key+C)/2 < 0 always; negative
// floats order reversed as u32 -> min_u32 on bits == min on key.
// Packed candidate = (acc_bits & ~1023) | chunk_local_row (v_and_or_b32,
// rowid regs shared across the 4 query-tiles).
// Selection: sorted-lowest-2-of-4 (8 ops) merged into kept sorted-3 via a
// 7-op network (v_min3 finish). Loss needs 3 of the true top-5 in the same
// 4-row group (P ~ 6e-9/query) or 4 in one 100-row subset (~5e-9) - safe.
// Tile loop fully unrolled, prefetch distance 2 (3-buffer rotation).
__global__ __launch_bounds__(256, 4) void knn_mfma(
        const uchar* __restrict__ xf8, const uchar* __restrict__ tf8,
        const float* __restrict__ t2c, uint32* __restrict__ cand_k) {
    __shared__ uint32 sk[4][MF_QPW][12];

    const int id   = blockIdx.x;
    const int r8   = id & 7, g = id >> 3;
    const int chunk = ((g >> 3) << 3) | r8;
    const int jq   = g & 7;                 // query-block within chunk
    const int tid  = threadIdx.x;
    const int wv   = tid >> 6;
    const int lane = tid & 63;
    const int quad = lane >> 4;
    const int c16  = lane & 15;
    const int qbase = jq * MF_QPB + wv * MF_QPW;
    const int n0 = chunk * MF_CHS;

    // B-fragments: 64 queries x K=128 fp8 in registers (8 VGPRs per qtile)
    i32x8 bq[4];
#pragma unroll
    for (int t = 0; t < 4; ++t)
        bq[t] = *(const i32x8*)(xf8 + (size_t)(qbase + t * 16 + c16) * DIM
                                + quad * 32);

    uint32 L0[4], L1[4], L2[4];
#pragma unroll
    for (int t = 0; t < 4; ++t) { L0[t] = 0xFFFFFFFFu; L1[t] = 0xFFFFFFFFu; L2[t] = 0xFFFFFFFFu; }

    const uchar* ap = tf8 + (size_t)(n0 + c16) * DIM + quad * 32;
    const float* tp = t2c + n0 + quad * 4;

    // 3-buffer rotation, prefetch distance 2, fully unrolled
    i32x8  F[3];
    float4 T[3];
    F[0] = *(const i32x8*)ap;                 T[0] = *(const float4*)tp;
    F[1] = *(const i32x8*)(ap + 16 * DIM);    T[1] = *(const float4*)(tp + 16);

    const uint32 rbase0 = (uint32)(quad * 4);  // chunk-local row of reg 0, tile 0

#pragma unroll
    for (int tile = 0; tile < MF_TILES; ++tile) {
        if (tile + 2 < MF_TILES) {
            F[(tile + 2) % 3] = *(const i32x8*)(ap + (size_t)(tile + 2) * 16 * DIM);
            T[(tile + 2) % 3] = *(const float4*)(tp + (tile + 2) * 16);
        }
        const i32x8  A  = F[tile % 3];
        const float4 tv = T[tile % 3];
        const uint32 r0 = rbase0 + (uint32)(tile * 16);   // +1,+2,+3 for regs 1..3

#pragma unroll
        for (int t = 0; t < 4; ++t) {
            f32x4 acc = (f32x4){tv.x, tv.y, tv.z, tv.w};
            acc = __builtin_amdgcn_mfma_scale_f32_16x16x128_f8f6f4(
                      A, bq[t], acc, 0, 0, 0, (int)SCALE1, 0, (int)SCALE1);
            // pack: v_and_or_b32 (rowid uniform across qtiles)
            uint32 p0 = (__float_as_uint(acc[0]) & 0xFFFFFC00u) | r0;
            uint32 p1 = (__float_as_uint(acc[1]) & 0xFFFFFC00u) | (r0 + 1);
            uint32 p2 = (__float_as_uint(acc[2]) & 0xFFFFFC00u) | (r0 + 2);
            uint32 p3 = (__float_as_uint(acc[3]) & 0xFFFFFC00u) | (r0 + 3);
            // sorted lowest-2 of 4 (8 ops)
            uint32 m0 = umn(p0, p1), M0 = umx(p0, p1);
            uint32 m1 = umn(p2, p3), M1 = umx(p2, p3);
            uint32 s0 = umn(m0, m1);
            uint32 s1 = umn(umx(m0, m1), umn(M0, M1));
            // merge sorted-2 into kept sorted-3 (7 ops, min3 finish)
            uint32 a0 = L0[t], a1 = L1[t], a2 = L2[t];
            uint32 m  = umn(a0, s0);
            uint32 M  = umx(a0, s0);
            uint32 n  = umn(a1, s1);
            uint32 N  = umx(a1, s1);
            uint32 l1 = umn(M, n);
            uint32 P  = umx(M, n);
            L0[t] = m;
            L1[t] = l1;
            L2[t] = umn(umn(P, N), a2);
        }
    }

    // 4 quads x sorted-3 = 12 candidates per query
#pragma unroll
    for (int t = 0; t < 4; ++t) {
        sk[wv][t * 16 + c16][quad * 3 + 0] = L0[t];
        sk[wv][t * 16 + c16][quad * 3 + 1] = L1[t];
        sk[wv][t * 16 + c16][quad * 3 + 2] = L2[t];
    }
    __syncthreads();

    // thread m owns block-query m: flat top-4 of 12 (branch-free network)
    const int mw = tid >> 6, ml = tid & 63;
    uint32 k0 = 0xFFFFFFFFu, k1 = 0xFFFFFFFFu, k2 = 0xFFFFFFFFu, k3 = 0xFFFFFFFFu;
#pragma unroll
    for (int j = 0; j < 12; ++j) {
        uint32 v = sk[mw][ml][j];
        uint32 t0 = umx(k0, v);
        k0 = umn(k0, v);
        uint32 t1 = umx(k1, t0);
        k1 = umn(k1, t0);
        uint32 t2_ = umx(k2, t1);
        k2 = umn(k2, t1);
        k3 = umn(k3, t2_);
    }
    // ids reconstructed in phase B: global_row = chunk*400 + (key & 1023)
    const size_t base = ((size_t)(jq * MF_QPB + tid) * MF_NCH + chunk) * MF_CSLOT;
    uint4 kk; kk.x = k0; kk.y = k1; kk.z = k2; kk.w = k3;
    *(uint4*)(cand_k + base) = kk;
}

// ---------------------------------------------------------------- phase B
// 4 queries per 256-thread block (one wave each). Stage 1: MF_RESCORE
// pure-VALU selection rounds over 1024 u32-keyed candidates. Stage 2: all
// rescore row-loads issued in parallel, exact fp32 d2, exact top-5,
// inverse-distance weighted average.
__global__ __launch_bounds__(256) void knn_final(
        const uint32* __restrict__ cand_k,
        const float* __restrict__ x, const float* __restrict__ train,
        const float* __restrict__ labels, float* __restrict__ out) {
    const int q = blockIdx.x * 4 + (threadIdx.x >> 6);
    const int lane = threadIdx.x & 63;
    const float xa = x[(size_t)q * DIM + lane];
    const float xb = x[(size_t)q * DIM + 64 + lane];

    uint32 ck[16]; uint32 cid[16];
    const size_t cb = (size_t)q * MF_NCAND;
#pragma unroll
    for (int j = 0; j < 16; ++j) {
        const int p = lane + 64 * j;               // slot; chunk = p>>2
        uint32 k = cand_k[cb + p];
        ck[j] = k;
        cid[j] = (uint32)(p >> 2) * MF_CHS + (k & 1023u);
    }

    // stage 1: select MF_RESCORE smallest (ck, cid) lexicographic
    uint32 selid[MF_RESCORE];
    uint32 tk = 0, ti = 0; bool first = true;
#pragma unroll
    for (int round = 0; round < MF_RESCORE; ++round) {
        uint32 mk = 0xFFFFFFFFu, mi = 0xFFFFFFFFu;
#pragma unroll
        for (int j = 0; j < 16; ++j) {
            bool gt = first || (ck[j] > tk) || (ck[j] == tk && cid[j] > ti);
            if (gt && ((ck[j] < mk) || (ck[j] == mk && cid[j] < mi))) {
                mk = ck[j]; mi = cid[j];
            }
        }
#pragma unroll
        for (int off = 32; off; off >>= 1) {
            uint32 ok = __shfl_xor(mk, off);
            uint32 oi = __shfl_xor(mi, off);
            if (ok < mk || (ok == mk && oi < mi)) { mk = ok; mi = oi; }
        }
        selid[round] = mi;
        tk = mk; ti = mi; first = false;
    }

    // stage 2: parallel exact fp32 rescore of all selected rows
    float d2v[MF_RESCORE];
#pragma unroll
    for (int r = 0; r < MF_RESCORE; ++r) {
        const float* tr = train + (size_t)selid[r] * DIM;
        float da = xa - tr[lane];
        float db = xb - tr[64 + lane];
        d2v[r] = fmaf(da, da, db * db);
    }
#pragma unroll
    for (int r = 0; r < MF_RESCORE; ++r) {
#pragma unroll
        for (int off = 32; off; off >>= 1) d2v[r] += __shfl_xor(d2v[r], off);
    }

    float bd0 = FLT_BIG, bd1 = FLT_BIG, bd2 = FLT_BIG, bd3 = FLT_BIG, bd4 = FLT_BIG;
    int   bi0 = 0, bi1 = 0, bi2 = 0, bi3 = 0, bi4 = 0;
#pragma unroll
    for (int r = 0; r < MF_RESCORE; ++r) {
        float v = d2v[r]; int id = (int)selid[r];
        TOP5_INSERT(v, id);
    }

    float d0 = sqrtf(fmaxf(bd0, 0.f));
    float d1 = sqrtf(fmaxf(bd1, 0.f));
    float d2_ = sqrtf(fmaxf(bd2, 0.f));
    float d3 = sqrtf(fmaxf(bd3, 0.f));
    float d4 = sqrtf(fmaxf(bd4, 0.f));
    bool zero = (d0 == 0.f) || (d1 == 0.f) || (d2_ == 0.f) || (d3 == 0.f) || (d4 == 0.f);
    float w0, w1, w2, w3, w4;
    if (zero) {
        w0 = (d0 == 0.f) ? 1.f : 0.f;
        w1 = (d1 == 0.f) ? 1.f : 0.f;
        w2 = (d2_ == 0.f) ? 1.f : 0.f;
        w3 = (d3 == 0.f) ? 1.f : 0.f;
        w4 = (d4 == 0.f) ? 1.f : 0.f;
    } else {
        w0 = 1.f / d0; w1 = 1.f / d1; w2 = 1.f / d2_; w3 = 1.f / d3; w4 = 1.f / d4;
    }
    float wsum = w0 + w1 + w2 + w3 + w4;
    float lsum = w0 * labels[bi0] + w1 * labels[bi1] + w2 * labels[bi2]
               + w3 * labels[bi3] + w4 * labels[bi4];
    if (lane == 0) out[q] = lsum / wsum;
}

// ======================= fallback path (round-1, fp32) =====================
#define FB_QT     16
#define FB_NCHUNK 25
#define FB_NT     256

__global__ void rowsq_kernel(const float* __restrict__ data,
                             float* __restrict__ out, int rows) {
    int r = blockIdx.x * blockDim.x + threadIdx.x;
    if (r >= rows) return;
    const float4* p = (const float4*)(data + (size_t)r * DIM);
    float s0 = 0.f, s1 = 0.f, s2 = 0.f, s3 = 0.f;
#pragma unroll
    for (int i = 0; i < DIM / 4; ++i) {
        float4 v = p[i];
        s0 += v.x * v.x; s1 += v.y * v.y; s2 += v.z * v.z; s3 += v.w * v.w;
    }
    out[r] = (s0 + s1) + (s2 + s3);
}

__global__ __launch_bounds__(FB_NT) void fb_phaseA(
        const float* __restrict__ x, const float* __restrict__ train,
        const float* __restrict__ x2, const float* __restrict__ t2,
        float* __restrict__ cand_d, int* __restrict__ cand_i,
        int N, int chunkSize) {
    __shared__ float xs[FB_QT][DIM + 4];
    __shared__ float rd[FB_QT][16 * KNN_K];
    __shared__ int   ri[FB_QT][16 * KNN_K];

    const int q0 = blockIdx.x * FB_QT;
    const int chunk = blockIdx.y;
    const int n0 = chunk * chunkSize;
    const int n1 = min(n0 + chunkSize, N);
    const int t = threadIdx.x;

    for (int i = t; i < FB_QT * DIM; i += FB_NT) {
        int q = i >> 7, d = i & (DIM - 1);
        xs[q][d] = x[(size_t)(q0 + q) * DIM + d];
    }
    __syncthreads();

    const int q  = t & (FB_QT - 1);
    const int ln = t >> 4;
    const float myx2 = x2[q0 + q];
    const float4* xp = (const float4*)xs[q];

    float bd0 = FLT_BIG, bd1 = FLT_BIG, bd2 = FLT_BIG, bd3 = FLT_BIG, bd4 = FLT_BIG;
    int   bi0 = -1, bi1 = -1, bi2 = -1, bi3 = -1, bi4 = -1;

    int n = n0 + ln;
    for (; n < n1; n += 16) {
        const float4* r0 = (const float4*)(train + (size_t)n * DIM);
        float dA = 0.f;
#pragma unroll 8
        for (int i = 0; i < DIM / 4; ++i) {
            float4 a = xp[i], b0 = r0[i];
            dA += a.x * b0.x + a.y * b0.y + a.z * b0.z + a.w * b0.w;
        }
        float vA = myx2 - 2.f * dA + t2[n];
        TOP5_INSERT(vA, n);
    }

    rd[q][ln * KNN_K + 0] = bd0;  ri[q][ln * KNN_K + 0] = bi0;
    rd[q][ln * KNN_K + 1] = bd1;  ri[q][ln * KNN_K + 1] = bi1;
    rd[q][ln * KNN_K + 2] = bd2;  ri[q][ln * KNN_K + 2] = bi2;
    rd[q][ln * KNN_K + 3] = bd3;  ri[q][ln * KNN_K + 3] = bi3;
    rd[q][ln * KNN_K + 4] = bd4;  ri[q][ln * KNN_K + 4] = bi4;
    __syncthreads();

    if (t < FB_QT) {
        float* dq = rd[t]; int* iq = ri[t];
        size_t base = ((size_t)(q0 + t) * FB_NCHUNK + chunk) * KNN_K;
#pragma unroll
        for (int k = 0; k < KNN_K; ++k) {
            float best = FLT_BIG; int bj = 0;
            for (int j = 0; j < 16 * KNN_K; ++j) {
                float v = dq[j];
                if (v < best) { best = v; bj = j; }
            }
            cand_d[base + k] = best; cand_i[base + k] = iq[bj];
            dq[bj] = FLT_BIG;
        }
    }
}

__global__ void fb_phaseB(const float* __restrict__ cand_d,
                          const int* __restrict__ cand_i,
                          const float* __restrict__ labels,
                          float* __restrict__ out, int B, int ncand) {
    int qq = blockIdx.x * blockDim.x + threadIdx.x;
    if (qq >= B) return;
    const float* cd = cand_d + (size_t)qq * ncand;
    const int*   ci = cand_i + (size_t)qq * ncand;

    float bd0 = FLT_BIG, bd1 = FLT_BIG, bd2 = FLT_BIG, bd3 = FLT_BIG, bd4 = FLT_BIG;
    int   bi0 = -1, bi1 = -1, bi2 = -1, bi3 = -1, bi4 = -1;
    for (int j = 0; j < ncand; ++j) {
        float v = cd[j]; int id = ci[j];
        TOP5_INSERT(v, id);
    }
    float d0 = sqrtf(fmaxf(bd0, 0.f));
    float d1 = sqrtf(fmaxf(bd1, 0.f));
    float d2 = sqrtf(fmaxf(bd2, 0.f));
    float d3 = sqrtf(fmaxf(bd3, 0.f));
    float d4 = sqrtf(fmaxf(bd4, 0.f));
    bool zero = (d0 == 0.f) || (d1 == 0.f) || (d2 == 0.f) || (d3 == 0.f) || (d4 == 0.f);
    float w0, w1, w2, w3, w4;
    if (zero) {
        w0 = (d0 == 0.f) ? 1.f : 0.f;
        w1 = (d1 == 0.f) ? 1.f : 0.f;
        w2 = (d2 == 0.f) ? 1.f : 0.f;
        w3 = (d3 == 0.f) ? 1.f : 0.f;
        w4 = (d4 == 0.f) ? 1.f : 0.f;
    } else {
        w0 = 1.f / d0; w1 = 1.f / d1; w2 = 1.f / d2; w3 = 1.f / d3; w4 = 1.f / d4;
    }
    float wsum = w0 + w1 + w2 + w3 + w4;
    float lsum = w0 * labels[bi0] + w1 * labels[bi1] + w2 * labels[bi2]
               + w3 * labels[bi3] + w4 * labels[bi4];
    out[qq] = lsum / wsum;
}

// ---------------------------------------------------------------- launch
static inline size_t align256(size_t v) { return (v + 255) & ~(size_t)255; }

extern "C" void kernel_launch(void* const* d_in, const int* in_sizes, int n_in,
                              void* d_out, int out_size, void* d_ws, size_t ws_size,
                              hipStream_t stream) {
    const float* x      = (const float*)d_in[0];   // [B, D] fp32
    const float* train  = (const float*)d_in[1];   // [N, D] fp32
    const float* labels = (const float*)d_in[2];   // [N]    fp32

    const int N = in_sizes[2];
    const int D = in_sizes[1] / N;
    const int B = in_sizes[0] / D;
    (void)n_in;

    size_t o_tf8 = 0;
    size_t o_xf8 = align256(o_tf8 + (size_t)MF_NPAD * DIM);
    size_t o_t2c = align256(o_xf8 + (size_t)B * DIM);
    size_t o_ck  = align256(o_t2c + (size_t)MF_NPAD * sizeof(float));
    size_t need  = align256(o_ck + (size_t)B * MF_NCAND * sizeof(uint32));

    const bool mfma_ok = (N == MF_N) && (D == DIM) && (B == MF_B) && (ws_size >= need);

    if (mfma_ok) {
        uchar* tf8 = (uchar*)d_ws + o_tf8;
        uchar* xf8 = (uchar*)d_ws + o_xf8;
        float* t2c = (float*)((char*)d_ws + o_t2c);
        uint32* cand_k = (uint32*)((char*)d_ws + o_ck);

        prep_kernel<<<MF_NPAD / 64 + MF_B / 64, 256, 0, stream>>>(
            train, x, tf8, xf8, t2c);
        knn_mfma<<<MF_NCH * 8, 256, 0, stream>>>(xf8, tf8, t2c, cand_k);
        knn_final<<<MF_B / 4, 256, 0, stream>>>(cand_k, x, train, labels,
                                                (float*)d_out);
    } else {
        float* t2     = (float*)d_ws;
        float* x2v    = t2 + N;
        float* cand_d = x2v + B;
        int*   cand_i = (int*)(cand_d + (size_t)B * FB_NCHUNK * KNN_K);

        rowsq_kernel<<<(N + 255) / 256, 256, 0, stream>>>(train, t2, N);
        rowsq_kernel<<<(B + 255) / 256, 256, 0, stream>>>(x, x2v, B);
        const int chunkSize = (N + FB_NCHUNK - 1) / FB_NCHUNK;
        dim3 gridA(B / FB_QT, FB_NCHUNK);
        fb_phaseA<<<gridA, FB_NT, 0, stream>>>(x, train, x2v, t2,
                                               cand_d, cand_i, N, chunkSize);
        fb_phaseB<<<(B + 255) / 256, 256, 0, stream>>>(cand_d, cand_i, labels,
                                                       (float*)d_out, B,
                                                       FB_NCHUNK * KNN_K);
    }
}

// Round 8
// 191.088 us; speedup vs baseline: 4.5371x; 4.5371x over previous
//
#include <hip/hip_runtime.h>
#include <math.h>

typedef __attribute__((ext_vector_type(8))) int   i32x8;
typedef __attribute__((ext_vector_type(4))) float f32x4;
typedef unsigned int uint32;
typedef unsigned char uchar;

#define KNN_K   5
#define DIM     128
#define FLT_BIG 3.402823466e38f
#define KEY_C   512.0f          // shift so acc = -(key+C)/2 is always negative

// ---------------- MFMA-path constants (fixed problem shape) ----------------
#define MF_B     2048
#define MF_N     100000
#define MF_QPB   256              // queries per block (4 waves x 64)
#define MF_QPW   64
#define MF_NCH   256              // train chunks (8 query-blocks each -> 2048 blocks)
#define MF_CHS   400              // rows per chunk; 256*400 = 102400 (padded)
#define MF_NPAD  (MF_NCH * MF_CHS)
#define MF_CSLOT 4                // candidates kept per (query, chunk)
#define MF_NCAND (MF_NCH * MF_CSLOT)   // 1024 per query = 16/lane exactly
#define MF_RESCORE 16             // phase-B exact-rescore depth (fp8 key noise)
#define SCALE1   0x7F7F7F7Fu      // E8M0 exponent 127 -> x1.0 in every byte

__device__ __forceinline__ uint32 umn(uint32 a, uint32 b) { return a < b ? a : b; }
__device__ __forceinline__ uint32 umx(uint32 a, uint32 b) { return a > b ? a : b; }

// Static-index top-5 insertion for exact fp32 phase-B merge.
#define TOP5_INSERT(v, id)                                                  \
    if ((v) < bd4) {                                                        \
        bool l0 = (v) < bd0, l1 = (v) < bd1, l2 = (v) < bd2, l3 = (v) < bd3;\
        if (l3) { bd4 = bd3; bi4 = bi3; } else { bd4 = (v); bi4 = (id); }   \
        if (l2) { bd3 = bd2; bi3 = bi2; } else if (l3) { bd3 = (v); bi3 = (id); } \
        if (l1) { bd2 = bd1; bi2 = bi1; } else if (l2) { bd2 = (v); bi2 = (id); } \
        if (l0) { bd1 = bd0; bi1 = bi0; } else if (l1) { bd1 = (v); bi1 = (id); } \
        if (l0) { bd0 = (v); bi0 = (id); }                                  \
    }

// ------------------------------------------------------------------- fp8 cvt
#if defined(__has_builtin) && __has_builtin(__builtin_amdgcn_cvt_pk_fp8_f32)
#define HAVE_CVT_FP8 1
#else
#define HAVE_CVT_FP8 0
__device__ __forceinline__ uint32 f2fp8_u(float f) {
    uint32 u = __float_as_uint(f);
    uint32 s = (u >> 31) << 7;
    uint32 au = u & 0x7FFFFFFFu;
    float a = __uint_as_float(au);
    if (a >= 448.f) return s | 0x7Eu;
    int ex = (int)((au >> 23) & 0xFF) - 127;
    if (ex < -6) {
        int m = (int)(a * 512.f + 0.5f);
        return s | (uint32)(m > 7 ? 7 : m);
    }
    uint32 r = au + 0x7FFFFu + ((au >> 20) & 1u);
    ex = (int)((r >> 23) & 0xFF) - 127;
    if (ex > 8) return s | 0x7Eu;
    return s | ((uint32)(ex + 7) << 3) | ((r >> 20) & 7u);
}
#endif

// ------------------------------------------------------------------- prep
// One launch: blocks [0, MF_NPAD/64) convert train (+pad key poison),
// blocks [MF_NPAD/64, +B/64) convert x. 16 rows/wave, lane = 32 floats.
__global__ __launch_bounds__(256) void prep_kernel(
        const float* __restrict__ train, const float* __restrict__ x,
        uchar* __restrict__ tf8, uchar* __restrict__ xf8,
        float* __restrict__ t2c) {
    const int wv = threadIdx.x >> 6, lane = threadIdx.x & 63;
    const int tblocks = MF_NPAD / 64;
    const bool isx = (blockIdx.x >= tblocks);
    const int blk = isx ? (blockIdx.x - tblocks) : blockIdx.x;
    const int row = (blk * 4 + wv) * 16 + (lane >> 2);

    const float* src; uchar* dst;
    if (isx) {
        if (row >= MF_B) return;
        src = x; dst = xf8;
    } else {
        if (row >= MF_N) {                        // pad row: poison key only
            if (row < MF_NPAD && (lane & 3) == 0) t2c[row] = -1e30f;
            return;
        }
        src = train; dst = tf8;
    }
    const int seg = (lane & 3) * 32;              // 32 floats / 32 bytes
    const float4* p = (const float4*)(src + (size_t)row * DIM + seg);

    float4 v[8];
#pragma unroll
    for (int j = 0; j < 8; ++j) v[j] = p[j];

    uint32 d[8];
#pragma unroll
    for (int j = 0; j < 8; ++j) {
#if HAVE_CVT_FP8
        int r = __builtin_amdgcn_cvt_pk_fp8_f32(v[j].x, v[j].y, 0, false);
        r = __builtin_amdgcn_cvt_pk_fp8_f32(v[j].z, v[j].w, r, true);
        d[j] = (uint32)r;
#else
        d[j] = f2fp8_u(v[j].x) | (f2fp8_u(v[j].y) << 8)
             | (f2fp8_u(v[j].z) << 16) | (f2fp8_u(v[j].w) << 24);
#endif
    }
    uint4* o = (uint4*)(dst + (size_t)row * DIM + seg);
    o[0] = make_uint4(d[0], d[1], d[2], d[3]);
    o[1] = make_uint4(d[4], d[5], d[6], d[7]);

    if (!isx) {
        float s = 0.f;
#pragma unroll
        for (int j = 0; j < 8; ++j)
            s += v[j].x * v[j].x + v[j].y * v[j].y + v[j].z * v[j].z + v[j].w * v[j].w;
        s += __shfl_xor(s, 1);
        s += __shfl_xor(s, 2);
        if ((lane & 3) == 0) t2c[row] = -(s + KEY_C) * 0.5f;
    }
}

// ---------------------------------------------------------------- phase A
// MX-fp8 K=128, XCD-affinity grid mapping (FETCH 104->15 MB, round 5).
// acc init = t2c = -(t2+C)/2 -> final acc = -(key+C)/2 < 0 always; negative
// floats order reversed as u32 -> min_u32 on bits == min on key.
// Packed candidate = (acc_bits & ~1023) | chunk_local_row.
// Selection: sorted-lowest-2-of-4 (8 ops) merged into kept sorted-3 via a
// 7-op network (min3 finish). Loss needs 3 of the true top-5 in one 4-row
// group (P ~ 6e-9/query) - safe; exact-fp32 rescore in phase B regardless.
// Pipeline: EXPLICIT fa/fb double-buffer, rolled 12x2-tile loop. NOTE
// (round-7 post-mortem): modulo-indexed rotation buffers (F[(t+2)%3]) spill
// to scratch (2.4 GB traffic, 6x regression) - keep buffers as named regs.
__global__ __launch_bounds__(256, 4) void knn_mfma(
        const uchar* __restrict__ xf8, const uchar* __restrict__ tf8,
        const float* __restrict__ t2c, uint32* __restrict__ cand_k) {
    __shared__ uint32 sk[4][MF_QPW][12];

    const int id   = blockIdx.x;
    const int r8   = id & 7, g = id >> 3;
    const int chunk = ((g >> 3) << 3) | r8;
    const int jq   = g & 7;                 // query-block within chunk
    const int tid  = threadIdx.x;
    const int wv   = tid >> 6;
    const int lane = tid & 63;
    const int quad = lane >> 4;
    const int c16  = lane & 15;
    const int qbase = jq * MF_QPB + wv * MF_QPW;
    const int n0 = chunk * MF_CHS;

    // B-fragments: 64 queries x K=128 fp8 in registers (8 VGPRs per qtile)
    i32x8 bq[4];
#pragma unroll
    for (int t = 0; t < 4; ++t)
        bq[t] = *(const i32x8*)(xf8 + (size_t)(qbase + t * 16 + c16) * DIM
                                + quad * 32);

    uint32 L0[4], L1[4], L2[4];
#pragma unroll
    for (int t = 0; t < 4; ++t) { L0[t] = 0xFFFFFFFFu; L1[t] = 0xFFFFFFFFu; L2[t] = 0xFFFFFFFFu; }

    const uchar* ap = tf8 + (size_t)(n0 + c16) * DIM + quad * 32;
    const float* tp = t2c + n0 + quad * 4;

    // MFMA + branch-free selection for one 16-row tile held in F
    auto process = [&](i32x8 F, float4 tv, uint32 r0) {
#pragma unroll
        for (int t = 0; t < 4; ++t) {
            f32x4 acc = (f32x4){tv.x, tv.y, tv.z, tv.w};
            acc = __builtin_amdgcn_mfma_scale_f32_16x16x128_f8f6f4(
                      F, bq[t], acc, 0, 0, 0, (int)SCALE1, 0, (int)SCALE1);
            // pack: v_and_or_b32 (rowid uniform across qtiles)
            uint32 p0 = (__float_as_uint(acc[0]) & 0xFFFFFC00u) | r0;
            uint32 p1 = (__float_as_uint(acc[1]) & 0xFFFFFC00u) | (r0 + 1);
            uint32 p2 = (__float_as_uint(acc[2]) & 0xFFFFFC00u) | (r0 + 2);
            uint32 p3 = (__float_as_uint(acc[3]) & 0xFFFFFC00u) | (r0 + 3);
            // sorted lowest-2 of 4 (8 ops)
            uint32 m0 = umn(p0, p1), M0 = umx(p0, p1);
            uint32 m1 = umn(p2, p3), M1 = umx(p2, p3);
            uint32 s0 = umn(m0, m1);
            uint32 s1 = umn(umx(m0, m1), umn(M0, M1));
            // merge sorted-2 into kept sorted-3 (7 ops, min3 finish)
            uint32 a0 = L0[t], a1 = L1[t], a2 = L2[t];
            uint32 m  = umn(a0, s0);
            uint32 M  = umx(a0, s0);
            uint32 n  = umn(a1, s1);
            uint32 N  = umx(a1, s1);
            uint32 l1 = umn(M, n);
            uint32 P  = umx(M, n);
            L0[t] = m;
            L1[t] = l1;
            L2[t] = umn(umn(P, N), a2);
        }
    };

    // explicit 2-tile double-buffered pipeline over 25 tiles
    i32x8 fa, fb;
    float4 tva, tvb;
    fa = *(const i32x8*)ap;
    tva = *(const float4*)tp;

    uint32 r0 = (uint32)(quad * 4);
    for (int it = 0; it < 12; ++it) {
        fb = *(const i32x8*)(ap + 16 * DIM);
        tvb = *(const float4*)(tp + 16);
        process(fa, tva, r0);
        fa = *(const i32x8*)(ap + 32 * DIM);
        tva = *(const float4*)(tp + 32);
        process(fb, tvb, r0 + 16);
        ap += 32 * DIM; tp += 32; r0 += 32;
    }
    process(fa, tva, r0);                   // tile 24

    // 4 quads x sorted-3 = 12 candidates per query
#pragma unroll
    for (int t = 0; t < 4; ++t) {
        sk[wv][t * 16 + c16][quad * 3 + 0] = L0[t];
        sk[wv][t * 16 + c16][quad * 3 + 1] = L1[t];
        sk[wv][t * 16 + c16][quad * 3 + 2] = L2[t];
    }
    __syncthreads();

    // thread m owns block-query m: flat top-4 of 12 (branch-free network)
    const int mw = tid >> 6, ml = tid & 63;
    uint32 k0 = 0xFFFFFFFFu, k1 = 0xFFFFFFFFu, k2 = 0xFFFFFFFFu, k3 = 0xFFFFFFFFu;
#pragma unroll
    for (int j = 0; j < 12; ++j) {
        uint32 v = sk[mw][ml][j];
        uint32 t0 = umx(k0, v);
        k0 = umn(k0, v);
        uint32 t1 = umx(k1, t0);
        k1 = umn(k1, t0);
        uint32 t2_ = umx(k2, t1);
        k2 = umn(k2, t1);
        k3 = umn(k3, t2_);
    }
    // ids reconstructed in phase B: global_row = chunk*400 + (key & 1023)
    const size_t base = ((size_t)(jq * MF_QPB + tid) * MF_NCH + chunk) * MF_CSLOT;
    uint4 kk; kk.x = k0; kk.y = k1; kk.z = k2; kk.w = k3;
    *(uint4*)(cand_k + base) = kk;
}

// ---------------------------------------------------------------- phase B
// 4 queries per 256-thread block (one wave each). Stage 1: MF_RESCORE
// pure-VALU selection rounds over 1024 u32-keyed candidates. Stage 2: all
// rescore row-loads issued in parallel, exact fp32 d2, exact top-5,
// inverse-distance weighted average.
__global__ __launch_bounds__(256) void knn_final(
        const uint32* __restrict__ cand_k,
        const float* __restrict__ x, const float* __restrict__ train,
        const float* __restrict__ labels, float* __restrict__ out) {
    const int q = blockIdx.x * 4 + (threadIdx.x >> 6);
    const int lane = threadIdx.x & 63;
    const float xa = x[(size_t)q * DIM + lane];
    const float xb = x[(size_t)q * DIM + 64 + lane];

    uint32 ck[16]; uint32 cid[16];
    const size_t cb = (size_t)q * MF_NCAND;
#pragma unroll
    for (int j = 0; j < 16; ++j) {
        const int p = lane + 64 * j;               // slot; chunk = p>>2
        uint32 k = cand_k[cb + p];
        ck[j] = k;
        cid[j] = (uint32)(p >> 2) * MF_CHS + (k & 1023u);
    }

    // stage 1: select MF_RESCORE smallest (ck, cid) lexicographic
    uint32 selid[MF_RESCORE];
    uint32 tk = 0, ti = 0; bool first = true;
#pragma unroll
    for (int round = 0; round < MF_RESCORE; ++round) {
        uint32 mk = 0xFFFFFFFFu, mi = 0xFFFFFFFFu;
#pragma unroll
        for (int j = 0; j < 16; ++j) {
            bool gt = first || (ck[j] > tk) || (ck[j] == tk && cid[j] > ti);
            if (gt && ((ck[j] < mk) || (ck[j] == mk && cid[j] < mi))) {
                mk = ck[j]; mi = cid[j];
            }
        }
#pragma unroll
        for (int off = 32; off; off >>= 1) {
            uint32 ok = __shfl_xor(mk, off);
            uint32 oi = __shfl_xor(mi, off);
            if (ok < mk || (ok == mk && oi < mi)) { mk = ok; mi = oi; }
        }
        selid[round] = mi;
        tk = mk; ti = mi; first = false;
    }

    // stage 2: parallel exact fp32 rescore of all selected rows
    float d2v[MF_RESCORE];
#pragma unroll
    for (int r = 0; r < MF_RESCORE; ++r) {
        const float* tr = train + (size_t)selid[r] * DIM;
        float da = xa - tr[lane];
        float db = xb - tr[64 + lane];
        d2v[r] = fmaf(da, da, db * db);
    }
#pragma unroll
    for (int r = 0; r < MF_RESCORE; ++r) {
#pragma unroll
        for (int off = 32; off; off >>= 1) d2v[r] += __shfl_xor(d2v[r], off);
    }

    float bd0 = FLT_BIG, bd1 = FLT_BIG, bd2 = FLT_BIG, bd3 = FLT_BIG, bd4 = FLT_BIG;
    int   bi0 = 0, bi1 = 0, bi2 = 0, bi3 = 0, bi4 = 0;
#pragma unroll
    for (int r = 0; r < MF_RESCORE; ++r) {
        float v = d2v[r]; int id = (int)selid[r];
        TOP5_INSERT(v, id);
    }

    float d0 = sqrtf(fmaxf(bd0, 0.f));
    float d1 = sqrtf(fmaxf(bd1, 0.f));
    float d2_ = sqrtf(fmaxf(bd2, 0.f));
    float d3 = sqrtf(fmaxf(bd3, 0.f));
    float d4 = sqrtf(fmaxf(bd4, 0.f));
    bool zero = (d0 == 0.f) || (d1 == 0.f) || (d2_ == 0.f) || (d3 == 0.f) || (d4 == 0.f);
    float w0, w1, w2, w3, w4;
    if (zero) {
        w0 = (d0 == 0.f) ? 1.f : 0.f;
        w1 = (d1 == 0.f) ? 1.f : 0.f;
        w2 = (d2_ == 0.f) ? 1.f : 0.f;
        w3 = (d3 == 0.f) ? 1.f : 0.f;
        w4 = (d4 == 0.f) ? 1.f : 0.f;
    } else {
        w0 = 1.f / d0; w1 = 1.f / d1; w2 = 1.f / d2_; w3 = 1.f / d3; w4 = 1.f / d4;
    }
    float wsum = w0 + w1 + w2 + w3 + w4;
    float lsum = w0 * labels[bi0] + w1 * labels[bi1] + w2 * labels[bi2]
               + w3 * labels[bi3] + w4 * labels[bi4];
    if (lane == 0) out[q] = lsum / wsum;
}

// ======================= fallback path (round-1, fp32) =====================
#define FB_QT     16
#define FB_NCHUNK 25
#define FB_NT     256

__global__ void rowsq_kernel(const float* __restrict__ data,
                             float* __restrict__ out, int rows) {
    int r = blockIdx.x * blockDim.x + threadIdx.x;
    if (r >= rows) return;
    const float4* p = (const float4*)(data + (size_t)r * DIM);
    float s0 = 0.f, s1 = 0.f, s2 = 0.f, s3 = 0.f;
#pragma unroll
    for (int i = 0; i < DIM / 4; ++i) {
        float4 v = p[i];
        s0 += v.x * v.x; s1 += v.y * v.y; s2 += v.z * v.z; s3 += v.w * v.w;
    }
    out[r] = (s0 + s1) + (s2 + s3);
}

__global__ __launch_bounds__(FB_NT) void fb_phaseA(
        const float* __restrict__ x, const float* __restrict__ train,
        const float* __restrict__ x2, const float* __restrict__ t2,
        float* __restrict__ cand_d, int* __restrict__ cand_i,
        int N, int chunkSize) {
    __shared__ float xs[FB_QT][DIM + 4];
    __shared__ float rd[FB_QT][16 * KNN_K];
    __shared__ int   ri[FB_QT][16 * KNN_K];

    const int q0 = blockIdx.x * FB_QT;
    const int chunk = blockIdx.y;
    const int n0 = chunk * chunkSize;
    const int n1 = min(n0 + chunkSize, N);
    const int t = threadIdx.x;

    for (int i = t; i < FB_QT * DIM; i += FB_NT) {
        int q = i >> 7, d = i & (DIM - 1);
        xs[q][d] = x[(size_t)(q0 + q) * DIM + d];
    }
    __syncthreads();

    const int q  = t & (FB_QT - 1);
    const int ln = t >> 4;
    const float myx2 = x2[q0 + q];
    const float4* xp = (const float4*)xs[q];

    float bd0 = FLT_BIG, bd1 = FLT_BIG, bd2 = FLT_BIG, bd3 = FLT_BIG, bd4 = FLT_BIG;
    int   bi0 = -1, bi1 = -1, bi2 = -1, bi3 = -1, bi4 = -1;

    int n = n0 + ln;
    for (; n < n1; n += 16) {
        const float4* r0 = (const float4*)(train + (size_t)n * DIM);
        float dA = 0.f;
#pragma unroll 8
        for (int i = 0; i < DIM / 4; ++i) {
            float4 a = xp[i], b0 = r0[i];
            dA += a.x * b0.x + a.y * b0.y + a.z * b0.z + a.w * b0.w;
        }
        float vA = myx2 - 2.f * dA + t2[n];
        TOP5_INSERT(vA, n);
    }

    rd[q][ln * KNN_K + 0] = bd0;  ri[q][ln * KNN_K + 0] = bi0;
    rd[q][ln * KNN_K + 1] = bd1;  ri[q][ln * KNN_K + 1] = bi1;
    rd[q][ln * KNN_K + 2] = bd2;  ri[q][ln * KNN_K + 2] = bi2;
    rd[q][ln * KNN_K + 3] = bd3;  ri[q][ln * KNN_K + 3] = bi3;
    rd[q][ln * KNN_K + 4] = bd4;  ri[q][ln * KNN_K + 4] = bi4;
    __syncthreads();

    if (t < FB_QT) {
        float* dq = rd[t]; int* iq = ri[t];
        size_t base = ((size_t)(q0 + t) * FB_NCHUNK + chunk) * KNN_K;
#pragma unroll
        for (int k = 0; k < KNN_K; ++k) {
            float best = FLT_BIG; int bj = 0;
            for (int j = 0; j < 16 * KNN_K; ++j) {
                float v = dq[j];
                if (v < best) { best = v; bj = j; }
            }
            cand_d[base + k] = best; cand_i[base + k] = iq[bj];
            dq[bj] = FLT_BIG;
        }
    }
}

__global__ void fb_phaseB(const float* __restrict__ cand_d,
                          const int* __restrict__ cand_i,
                          const float* __restrict__ labels,
                          float* __restrict__ out, int B, int ncand) {
    int qq = blockIdx.x * blockDim.x + threadIdx.x;
    if (qq >= B) return;
    const float* cd = cand_d + (size_t)qq * ncand;
    const int*   ci = cand_i + (size_t)qq * ncand;

    float bd0 = FLT_BIG, bd1 = FLT_BIG, bd2 = FLT_BIG, bd3 = FLT_BIG, bd4 = FLT_BIG;
    int   bi0 = -1, bi1 = -1, bi2 = -1, bi3 = -1, bi4 = -1;
    for (int j = 0; j < ncand; ++j) {
        float v = cd[j]; int id = ci[j];
        TOP5_INSERT(v, id);
    }
    float d0 = sqrtf(fmaxf(bd0, 0.f));
    float d1 = sqrtf(fmaxf(bd1, 0.f));
    float d2 = sqrtf(fmaxf(bd2, 0.f));
    float d3 = sqrtf(fmaxf(bd3, 0.f));
    float d4 = sqrtf(fmaxf(bd4, 0.f));
    bool zero = (d0 == 0.f) || (d1 == 0.f) || (d2 == 0.f) || (d3 == 0.f) || (d4 == 0.f);
    float w0, w1, w2, w3, w4;
    if (zero) {
        w0 = (d0 == 0.f) ? 1.f : 0.f;
        w1 = (d1 == 0.f) ? 1.f : 0.f;
        w2 = (d2 == 0.f) ? 1.f : 0.f;
        w3 = (d3 == 0.f) ? 1.f : 0.f;
        w4 = (d4 == 0.f) ? 1.f : 0.f;
    } else {
        w0 = 1.f / d0; w1 = 1.f / d1; w2 = 1.f / d2; w3 = 1.f / d3; w4 = 1.f / d4;
    }
    float wsum = w0 + w1 + w2 + w3 + w4;
    float lsum = w0 * labels[bi0] + w1 * labels[bi1] + w2 * labels[bi2]
               + w3 * labels[bi3] + w4 * labels[bi4];
    out[qq] = lsum / wsum;
}

// ---------------------------------------------------------------- launch
static inline size_t align256(size_t v) { return (v + 255) & ~(size_t)255; }

extern "C" void kernel_launch(void* const* d_in, const int* in_sizes, int n_in,
                              void* d_out, int out_size, void* d_ws, size_t ws_size,
                              hipStream_t stream) {
    const float* x      = (const float*)d_in[0];   // [B, D] fp32
    const float* train  = (const float*)d_in[1];   // [N, D] fp32
    const float* labels = (const float*)d_in[2];   // [N]    fp32

    const int N = in_sizes[2];
    const int D = in_sizes[1] / N;
    const int B = in_sizes[0] / D;
    (void)n_in;

    size_t o_tf8 = 0;
    size_t o_xf8 = align256(o_tf8 + (size_t)MF_NPAD * DIM);
    size_t o_t2c = align256(o_xf8 + (size_t)B * DIM);
    size_t o_ck  = align256(o_t2c + (size_t)MF_NPAD * sizeof(float));
    size_t need  = align256(o_ck + (size_t)B * MF_NCAND * sizeof(uint32));

    const bool mfma_ok = (N == MF_N) && (D == DIM) && (B == MF_B) && (ws_size >= need);

    if (mfma_ok) {
        uchar* tf8 = (uchar*)d_ws + o_tf8;
        uchar* xf8 = (uchar*)d_ws + o_xf8;
        float* t2c = (float*)((char*)d_ws + o_t2c);
        uint32* cand_k = (uint32*)((char*)d_ws + o_ck);

        prep_kernel<<<MF_NPAD / 64 + MF_B / 64, 256, 0, stream>>>(
            train, x, tf8, xf8, t2c);
        knn_mfma<<<MF_NCH * 8, 256, 0, stream>>>(xf8, tf8, t2c, cand_k);
        knn_final<<<MF_B / 4, 256, 0, stream>>>(cand_k, x, train, labels,
                                                (float*)d_out);
    } else {
        float* t2     = (float*)d_ws;
        float* x2v    = t2 + N;
        float* cand_d = x2v + B;
        int*   cand_i = (int*)(cand_d + (size_t)B * FB_NCHUNK * KNN_K);

        rowsq_kernel<<<(N + 255) / 256, 256, 0, stream>>>(train, t2, N);
        rowsq_kernel<<<(B + 255) / 256, 256, 0, stream>>>(x, x2v, B);
        const int chunkSize = (N + FB_NCHUNK - 1) / FB_NCHUNK;
        dim3 gridA(B / FB_QT, FB_NCHUNK);
        fb_phaseA<<<gridA, FB_NT, 0, stream>>>(x, train, x2v, t2,
                                               cand_d, cand_i, N, chunkSize);
        fb_phaseB<<<(B + 255) / 256, 256, 0, stream>>>(cand_d, cand_i, labels,
                                                       (float*)d_out, B,
                                                       FB_NCHUNK * KNN_K);
    }
}